// Round 3
// baseline (256.914 us; speedup 1.0000x reference)
//
#include <hip/hip_runtime.h>
#include <stdint.h>

#define EPS_F 1e-7f

typedef float f32x4 __attribute__((ext_vector_type(4)));

union U4 { uint4 u4; struct { long lo, hi; } l; };
union A8 { uint2 u2; long l; };

__device__ __forceinline__ int cvt4(float a, float b, float c, float d) {
  int v = __builtin_amdgcn_cvt_pk_fp8_f32(a, b, 0, false);   // bytes 0,1
  return __builtin_amdgcn_cvt_pk_fp8_f32(c, d, v, true);     // bytes 2,3
}

// ---------------------------------------------------------------------------
// prep: prototypes fp32 (2048x512) -> fp8 e4m3, pre-swizzled into MFMA
// B-fragment order for 16x16x32 fp8.  16-B chunk id = (g*8 + kp)*64 + q*16 + rl
// holds col c = g*16+rl, k = {2kp,2kp+1}*32 + q*8 + [0..8).  Also y2 (fp32
// exact) and zeroing of the output accumulator.
// One wave per proto row x 4 rows; coalesced 2KB row reads, shfl transpose.
// ---------------------------------------------------------------------------
__global__ __launch_bounds__(256) void prep_kernel(
    const float* __restrict__ protos, uint8_t* __restrict__ wsB,
    float* __restrict__ y2, float* __restrict__ out) {
  const int lane = threadIdx.x & 63;
  const int w    = threadIdx.x >> 6;
  const int kp   = lane >> 2, q = lane & 3;     // chunk coords (lanes 0..31)
  const int s0   = kp * 8 + q;                  // source lane of chunk half 0
#pragma unroll
  for (int i = 0; i < 4; ++i) {
    int c = (blockIdx.x * 4 + w) * 4 + i;
    const float4* p = (const float4*)(protos + (size_t)c * 512 + lane * 8);
    float4 f0 = p[0], f1 = p[1];
    float s = f0.x*f0.x + f0.y*f0.y + f0.z*f0.z + f0.w*f0.w
            + f1.x*f1.x + f1.y*f1.y + f1.z*f1.z + f1.w*f1.w;
#pragma unroll
    for (int off = 32; off > 0; off >>= 1) s += __shfl_xor(s, off, 64);
    if (lane == 0) y2[c] = s;
    int lo = cvt4(f0.x, f0.y, f0.z, f0.w);   // k+0..3 of this lane's 8
    int hi = cvt4(f1.x, f1.y, f1.z, f1.w);   // k+4..7
    uint4 ch;
    ch.x = __shfl(lo, s0, 64);      // kk=2kp  bytes 0-3
    ch.y = __shfl(hi, s0, 64);      //         bytes 4-7
    ch.z = __shfl(lo, s0 + 4, 64);  // kk=2kp+1
    ch.w = __shfl(hi, s0 + 4, 64);
    if (lane < 32) {
      int g = c >> 4, rl = c & 15;
      ((uint4*)wsB)[(g * 8 + kp) * 64 + q * 16 + rl] = ch;
    }
  }
  if (blockIdx.x == 0 && threadIdx.x == 0) out[0] = 0.f;
}

// ---------------------------------------------------------------------------
// gemm_min: grid 512 x 256 thr, __launch_bounds__(256,2) -> 2 blocks/CU
// (2 waves/SIMD).  NO LDS in the main loop, NO barriers in the main loop.
//   wave = 64 z-rows (A: fp32->fp8 converted once into 128 VGPRs; x2 exact
//   fp32 alongside) x 512 protos (quarter of wsB).  B: rolling 4-chunk
//   register prefetch from the L2-resident swizzled fp8 image.
//   Epilogue per 16-proto col-frag: running min of t = sqdist/max(denom,eps).
// ---------------------------------------------------------------------------
__global__ __launch_bounds__(256, 2) void gemm_min_kernel(
    const float* __restrict__ z, const uint8_t* __restrict__ wsB,
    const float* __restrict__ y2, const float* __restrict__ marg,
    float* __restrict__ out) {
  __shared__ float x2s[64];
  __shared__ float minbuf[64][4];

  const int tid  = threadIdx.x;
  const int lane = tid & 63;
  const int w    = tid >> 6;
  const int quad = lane >> 4;
  const int l15  = lane & 15;
  const size_t rowbase = (size_t)blockIdx.x * 64;

  // ---- A: load fp32, convert to fp8 frags in regs, exact fp32 x2 ----
  uint2 afr[4][16];  // 128 VGPRs: rf x kstep, 8 fp8 each (row=l15, k=quad*8+j)
  float ss[4];
#pragma unroll
  for (int rf = 0; rf < 4; ++rf) {
    const float* rp = z + (rowbase + rf * 16 + l15) * 512;
    float s = 0.f;
#pragma unroll
    for (int kk = 0; kk < 16; ++kk) {
      const float4* p = (const float4*)(rp + kk * 32 + quad * 8);
      float4 f0 = p[0], f1 = p[1];
      s += f0.x*f0.x + f0.y*f0.y + f0.z*f0.z + f0.w*f0.w
         + f1.x*f1.x + f1.y*f1.y + f1.z*f1.z + f1.w*f1.w;
      afr[rf][kk].x = (unsigned)cvt4(f0.x, f0.y, f0.z, f0.w);
      afr[rf][kk].y = (unsigned)cvt4(f1.x, f1.y, f1.z, f1.w);
    }
    s += __shfl_xor(s, 16, 64);
    s += __shfl_xor(s, 32, 64);   // sum across the 4 quads -> full row sum
    ss[rf] = s;
  }
  if (quad == 0) {
#pragma unroll
    for (int rf = 0; rf < 4; ++rf) x2s[rf * 16 + l15] = ss[rf];
  }
  __syncthreads();  // only pre-loop barrier
  float x2r[4][4];
#pragma unroll
  for (int rf = 0; rf < 4; ++rf)
#pragma unroll
    for (int r = 0; r < 4; ++r) x2r[rf][r] = x2s[rf * 16 + quad * 4 + r];

  // ---- main loop: 32 col-frags x 8 chunk-steps (K=64 per chunk-pair) ----
  const uint4* Bp = (const uint4*)wsB + (size_t)w * (256 * 64) + lane;
  uint4 Bw[4];
#pragma unroll
  for (int j = 0; j < 4; ++j) Bw[j] = Bp[j * 64];   // prime 4-deep pipeline

  float tmin[4][4];
#pragma unroll
  for (int rf = 0; rf < 4; ++rf)
#pragma unroll
    for (int r = 0; r < 4; ++r) tmin[rf][r] = 3.4e38f;

  const float* y2p = y2 + w * 512 + l15;

#pragma clang loop unroll(disable)
  for (int cf = 0; cf < 32; ++cf) {
    f32x4 acc[4];
#pragma unroll
    for (int rf = 0; rf < 4; ++rf) {
      f32x4 zz = {0.f, 0.f, 0.f, 0.f};
      acc[rf] = zz;
    }
#pragma unroll
    for (int kp = 0; kp < 8; ++kp) {
      U4 u; u.u4 = Bw[kp & 3];
      Bw[kp & 3] = Bp[(cf * 8 + kp + 4) * 64];   // prefetch distance 4
      long b0 = u.l.lo, b1 = u.l.hi;
#pragma unroll
      for (int rf = 0; rf < 4; ++rf) {
        A8 a0, a1;
        a0.u2 = afr[rf][2 * kp];
        a1.u2 = afr[rf][2 * kp + 1];
        acc[rf] = __builtin_amdgcn_mfma_f32_16x16x32_fp8_fp8(
            a0.l, b0, acc[rf], 0, 0, 0);
        acc[rf] = __builtin_amdgcn_mfma_f32_16x16x32_fp8_fp8(
            a1.l, b1, acc[rf], 0, 0, 0);
      }
    }
    // epilogue: cols = w*512 + cf*16 + l15
    float y2v = y2p[cf * 16];
    float omy = 1.f - y2v;
#pragma unroll
    for (int rf = 0; rf < 4; ++rf) {
#pragma unroll
      for (int r = 0; r < 4; ++r) {
        float x2v = x2r[rf][r];
        float den = fmaxf((1.f - x2v) * omy, EPS_F);
        float sq  = fmaxf(x2v + y2v - 2.f * acc[rf][r], 0.f);
        float t   = sq * __builtin_amdgcn_rcpf(den);
        tmin[rf][r] = fminf(tmin[rf][r], t);
      }
    }
  }

  // ---- reduce: min over the 16 lanes of each col group (same rows) ----
#pragma unroll
  for (int rf = 0; rf < 4; ++rf) {
#pragma unroll
    for (int r = 0; r < 4; ++r) {
      float v = tmin[rf][r];
      v = fminf(v, __shfl_xor(v, 1, 64));
      v = fminf(v, __shfl_xor(v, 2, 64));
      v = fminf(v, __shfl_xor(v, 4, 64));
      v = fminf(v, __shfl_xor(v, 8, 64));
      if (l15 == 0) minbuf[rf * 16 + quad * 4 + r][w] = v;  // row=quad*4+r
    }
  }
  __syncthreads();

  if (w == 0) {
    float m = fminf(fminf(minbuf[lane][0], minbuf[lane][1]),
                    fminf(minbuf[lane][2], minbuf[lane][3]));
    float arg = fmaxf(fmaf(2.f, m, 1.f), 1.f + EPS_F);
    float contrib = fmaxf(marg[0] - acoshf(arg), 0.f);
#pragma unroll
    for (int off = 32; off > 0; off >>= 1) contrib += __shfl_xor(contrib, off, 64);
    if (lane == 0) atomicAdd(out, contrib * (1.0f / 32768.f));
  }
}

// ---------------------------------------------------------------------------
extern "C" void kernel_launch(void* const* d_in, const int* in_sizes, int n_in,
                              void* d_out, int out_size, void* d_ws, size_t ws_size,
                              hipStream_t stream) {
  const float* z      = (const float*)d_in[0];  // 32768 x 512 fp32
  const float* protos = (const float*)d_in[1];  // 2048 x 512 fp32
  const float* marg   = (const float*)d_in[2];  // scalar
  float* out = (float*)d_out;
  uint8_t* wsB = (uint8_t*)d_ws;                                      // 1 MB
  // 8 KB pad after wsB absorbs the (harmless) tail prefetch over-reads.
  float* y2 = (float*)((char*)d_ws + (1 << 20) + 8192);               // 8 KB

  prep_kernel<<<128, 256, 0, stream>>>(protos, wsB, y2, out);
  gemm_min_kernel<<<512, 256, 0, stream>>>(z, wsB, y2, marg, out);
}

// Round 4
// 256.679 us; speedup vs baseline: 1.0009x; 1.0009x over previous
//
#include <hip/hip_runtime.h>
#include <stdint.h>

#define EPS_F 1e-7f

typedef float f32x16 __attribute__((ext_vector_type(16)));

union B16 { uint4 u4; struct { long lo, hi; } l; };
union A8 { uint2 u2; long l; };

__device__ __forceinline__ int cvt4(float a, float b, float c, float d) {
  int v = __builtin_amdgcn_cvt_pk_fp8_f32(a, b, 0, false);   // bytes 0,1
  return __builtin_amdgcn_cvt_pk_fp8_f32(c, d, v, true);     // bytes 2,3
}

// ---------------------------------------------------------------------------
// prep: prototypes fp32 (2048x512) -> fp8 e4m3 in MFMA B-fragment order for
// 32x32x16 fp8: 16-B chunk (g,kp), lane l holds col n = 32g + (l&31),
// bytes[0:8) = k in [32kp+8h, +8), bytes[8:16) = k in [32kp+16+8h, +8),
// h = l>>5.  Also y2[c] (fp32 exact) and ry[c] = 1/(1-y2) (denominator's
// max(.,EPS) never binds: omy >= 0.36 since points lie in radius-0.8 ball).
// One wave per proto row; coalesced row read + shfl transpose.
// ---------------------------------------------------------------------------
__global__ __launch_bounds__(256) void prep_kernel(
    const float* __restrict__ protos, uint8_t* __restrict__ wsB,
    float* __restrict__ y2a, float* __restrict__ rya,
    float* __restrict__ out) {
  const int lane = threadIdx.x & 63;
  const int w    = threadIdx.x >> 6;
#pragma unroll
  for (int i = 0; i < 4; ++i) {
    int c = (blockIdx.x * 4 + w) * 4 + i;
    const float4* p = (const float4*)(protos + (size_t)c * 512 + lane * 8);
    float4 f0 = p[0], f1 = p[1];
    float s = f0.x*f0.x + f0.y*f0.y + f0.z*f0.z + f0.w*f0.w
            + f1.x*f1.x + f1.y*f1.y + f1.z*f1.z + f1.w*f1.w;
#pragma unroll
    for (int off = 32; off > 0; off >>= 1) s += __shfl_xor(s, off, 64);
    if (lane == 0) { y2a[c] = s; rya[c] = 1.f / (1.f - s); }
    int ux = cvt4(f0.x, f0.y, f0.z, f0.w);   // k [8l, 8l+4)
    int uy = cvt4(f1.x, f1.y, f1.z, f1.w);   // k [8l+4, 8l+8)
    int kp = lane & 15, h = (lane >> 4) & 1;
    int s0 = 4 * kp + h;        // source lane for bytes[0:8)  (k 32kp+8h..)
    int s1 = 4 * kp + 2 + h;    // source lane for bytes[8:16) (k 32kp+16+8h..)
    uint4 ch;
    ch.x = __shfl(ux, s0, 64);
    ch.y = __shfl(uy, s0, 64);
    ch.z = __shfl(ux, s1, 64);
    ch.w = __shfl(uy, s1, 64);
    if (lane < 32) {
      int g = c >> 5, cl = c & 31;
      ((uint4*)wsB)[(g * 16 + kp) * 64 + cl + 32 * h] = ch;
    }
  }
  if (blockIdx.x == 0 && threadIdx.x == 0) out[0] = 0.f;
}

// ---------------------------------------------------------------------------
// gemm_min: 512 blocks x 256 thr, launch_bounds(256,3).  Block = 64 z-rows.
//   - A: fp32 -> fp8, staged ONCE into 32 KB LDS in A-fragment order
//     (chunk (kp,rf): same 16-B layout as B).  ONE barrier total.
//   - B: straight from the L2-resident 1 MB swizzled fp8 image into regs,
//     4-deep rolling prefetch.  Each wave owns a 512-col quarter.
//   - mfma_f32_32x32x16_fp8_fp8, 2 row-frags: one 8-B B chunk feeds 2 MFMAs
//     -> B L2 demand 28 B/cyc/CU (half the per-CU share); A LDS demand
//     56 B/cyc (vs 85 ceiling).
//   - epilogue per 32-col frag: running min of u = max(x2+y2-2dot,0)*ry;
//     rx = 1/(1-x2) applied once per row at the end (monotone factorization;
//     the max(denom,EPS) clamp never binds since omx,omy >= 0.36).
// ---------------------------------------------------------------------------
__global__ __launch_bounds__(256, 3) void gemm_min_kernel(
    const float* __restrict__ z, const uint8_t* __restrict__ wsB,
    const float* __restrict__ y2a, const float* __restrict__ rya,
    const float* __restrict__ marg, float* __restrict__ out) {
  __shared__ uint8_t As[32 * 1024];   // 32 chunks x 64 lanes x 16 B
  __shared__ float x2s[64];
  __shared__ float rxs[64];
  __shared__ float minbuf[64][4];

  const int tid  = threadIdx.x;
  const int lane = tid & 63;
  const int w    = tid >> 6;
  const int l31  = lane & 31;
  const int h    = lane >> 5;
  const size_t rowbase = (size_t)blockIdx.x * 64;

  // ---- x2 pass: coalesced row reads, exact fp32; also warms L2 for staging
  for (int j = 0; j < 16; ++j) {
    int row = w * 16 + j;
    const float4* p = (const float4*)(z + (rowbase + row) * 512 + lane * 8);
    float4 f0 = p[0], f1 = p[1];
    float s = f0.x*f0.x + f0.y*f0.y + f0.z*f0.z + f0.w*f0.w
            + f1.x*f1.x + f1.y*f1.y + f1.z*f1.z + f1.w*f1.w;
#pragma unroll
    for (int off = 32; off > 0; off >>= 1) s += __shfl_xor(s, off, 64);
    if (lane == 0) { x2s[row] = s; rxs[row] = 1.f / (1.f - s); }
  }

  // ---- A staging: transposed 16-B reads (lines fully consumed pair-wise),
  // conflict-free contiguous ds_write_b128.  chunk c = kp*2 + rf.
  for (int j = 0; j < 8; ++j) {
    int c  = w * 8 + j;
    int kp = c >> 1, rf = c & 1;
    int row = rf * 32 + l31;
    const float* rp = z + (rowbase + row) * 512 + kp * 32 + h * 8;
    float4 a0 = ((const float4*)rp)[0], a1 = ((const float4*)rp)[1];
    float4 b0 = ((const float4*)(rp + 16))[0], b1 = ((const float4*)(rp + 16))[1];
    uint4 ch;
    ch.x = (unsigned)cvt4(a0.x, a0.y, a0.z, a0.w);
    ch.y = (unsigned)cvt4(a1.x, a1.y, a1.z, a1.w);
    ch.z = (unsigned)cvt4(b0.x, b0.y, b0.z, b0.w);
    ch.w = (unsigned)cvt4(b1.x, b1.y, b1.z, b1.w);
    ((uint4*)As)[c * 64 + lane] = ch;
  }
  __syncthreads();  // the ONLY barrier before the reduction

  // ---- main loop: wave w covers cols [w*512, w*512+512) = 16 col-frags ----
  const uint4* Bp = (const uint4*)wsB + (size_t)(w * 256) * 64 + lane;
  const uint4* Apc = (const uint4*)As;
  uint4 Bw[4];
#pragma unroll
  for (int j = 0; j < 4; ++j) Bw[j] = Bp[j * 64];

  float tmin[2][16];
#pragma unroll
  for (int rf = 0; rf < 2; ++rf)
#pragma unroll
    for (int r = 0; r < 16; ++r) tmin[rf][r] = 3.4e38f;

  const float* y2p = y2a + w * 512 + l31;
  const float* ryp = rya + w * 512 + l31;

#pragma clang loop unroll(disable)
  for (int cf = 0; cf < 16; ++cf) {
    f32x16 acc0, acc1;
#pragma unroll
    for (int r = 0; r < 16; ++r) { acc0[r] = 0.f; acc1[r] = 0.f; }

#pragma unroll
    for (int kp = 0; kp < 16; ++kp) {
      B16 u; u.u4 = Bw[kp & 3];
      Bw[kp & 3] = Bp[(cf * 16 + kp + 4) * 64];   // rolling prefetch, dist 4
      uint4 av0 = Apc[(kp * 2 + 0) * 64 + lane];  // rf=0: [ks=2kp | ks=2kp+1]
      uint4 av1 = Apc[(kp * 2 + 1) * 64 + lane];  // rf=1
      A8 a00, a01, a10, a11;
      a00.u2 = make_uint2(av0.x, av0.y); a01.u2 = make_uint2(av0.z, av0.w);
      a10.u2 = make_uint2(av1.x, av1.y); a11.u2 = make_uint2(av1.z, av1.w);
      acc0 = __builtin_amdgcn_mfma_f32_32x32x16_fp8_fp8(a00.l, u.l.lo, acc0, 0, 0, 0);
      acc1 = __builtin_amdgcn_mfma_f32_32x32x16_fp8_fp8(a10.l, u.l.lo, acc1, 0, 0, 0);
      acc0 = __builtin_amdgcn_mfma_f32_32x32x16_fp8_fp8(a01.l, u.l.hi, acc0, 0, 0, 0);
      acc1 = __builtin_amdgcn_mfma_f32_32x32x16_fp8_fp8(a11.l, u.l.hi, acc1, 0, 0, 0);
    }

    // epilogue: cols n = w*512 + cf*32 + l31
    float y2v = y2p[cf * 32];
    float ryv = ryp[cf * 32];
#pragma unroll
    for (int rf = 0; rf < 2; ++rf) {
#pragma unroll
      for (int g = 0; g < 4; ++g) {
        // rows rf*32 + 8g + 4h + {0..3}  (C/D: row = (reg&3)+8*(reg>>2)+4h)
        float4 x4 = *(const float4*)&x2s[rf * 32 + 8 * g + 4 * h];
#pragma unroll
        for (int q = 0; q < 4; ++q) {
          int r = g * 4 + q;
          float x2v = (q == 0) ? x4.x : (q == 1) ? x4.y : (q == 2) ? x4.z : x4.w;
          float a = rf ? acc1[r] : acc0[r];
          float sq = fmaxf(fmaf(-2.f, a, x2v + y2v), 0.f);
          tmin[rf][r] = fminf(tmin[rf][r], sq * ryv);
        }
      }
    }
  }

  // ---- reduce: min across the 32 lanes sharing each row ----
#pragma unroll
  for (int rf = 0; rf < 2; ++rf) {
#pragma unroll
    for (int r = 0; r < 16; ++r) {
      float v = tmin[rf][r];
      v = fminf(v, __shfl_xor(v, 1, 64));
      v = fminf(v, __shfl_xor(v, 2, 64));
      v = fminf(v, __shfl_xor(v, 4, 64));
      v = fminf(v, __shfl_xor(v, 8, 64));
      v = fminf(v, __shfl_xor(v, 16, 64));
      if (l31 == 0) {
        int row = rf * 32 + (r & 3) + 8 * (r >> 2) + 4 * h;
        minbuf[row][w] = v;
      }
    }
  }
  __syncthreads();

  if (w == 0) {
    float m = fminf(fminf(minbuf[lane][0], minbuf[lane][1]),
                    fminf(minbuf[lane][2], minbuf[lane][3]));
    float t = m * rxs[lane];                      // apply 1/omx once per row
    float arg = fmaxf(fmaf(2.f, t, 1.f), 1.f + EPS_F);
    float contrib = fmaxf(marg[0] - acoshf(arg), 0.f);
#pragma unroll
    for (int off = 32; off > 0; off >>= 1) contrib += __shfl_xor(contrib, off, 64);
    if (lane == 0) atomicAdd(out, contrib * (1.0f / 32768.f));
  }
}

// ---------------------------------------------------------------------------
extern "C" void kernel_launch(void* const* d_in, const int* in_sizes, int n_in,
                              void* d_out, int out_size, void* d_ws, size_t ws_size,
                              hipStream_t stream) {
  const float* z      = (const float*)d_in[0];  // 32768 x 512 fp32
  const float* protos = (const float*)d_in[1];  // 2048 x 512 fp32
  const float* marg   = (const float*)d_in[2];  // scalar
  float* out = (float*)d_out;
  uint8_t* wsB = (uint8_t*)d_ws;                                 // 1 MB
  // 8 KB pad absorbs the harmless tail prefetch over-read (<= 4 KB).
  float* y2a = (float*)((char*)d_ws + (1 << 20) + 8192);         // 8 KB
  float* rya = y2a + 2048;                                       // 8 KB

  prep_kernel<<<128, 256, 0, stream>>>(protos, wsB, y2a, rya, out);
  gemm_min_kernel<<<512, 256, 0, stream>>>(z, wsB, y2a, rya, marg, out);
}

// Round 5
// 154.508 us; speedup vs baseline: 1.6628x; 1.6613x over previous
//
#include <hip/hip_runtime.h>
#include <stdint.h>

#define EPS_F 1e-7f

typedef float f32x4 __attribute__((ext_vector_type(4)));

union A8 { uint2 u2; long l; };

__device__ __forceinline__ unsigned cvt4(float a, float b, float c, float d) {
  int v = __builtin_amdgcn_cvt_pk_fp8_f32(a, b, 0, false);   // bytes 0,1
  return (unsigned)__builtin_amdgcn_cvt_pk_fp8_f32(c, d, v, true);  // bytes 2,3
}

// ---------------------------------------------------------------------------
// prep: prototypes fp32 (2048x512) -> fp8 e4m3 in MFMA B-fragment order for
// 16x16x32 fp8.  16-B chunk (g,kp2), lane l (q=l>>4, cl=l&15) holds
// col n = 16g + cl;  bytes[0:8) = k [64*kp2 + 8q, +8)         (even K32-step)
//                    bytes[8:16) = k [64*kp2 + 32 + 8q, +8)   (odd  K32-step)
// Also y2[c] = ||p_c||^2 (fp32 exact) and ry[c] = 1/(1-y2) (clamp never
// binds: all points inside radius-0.8 ball -> 1-y2 >= 0.36), and out=0.
// ---------------------------------------------------------------------------
__global__ __launch_bounds__(256) void prep_kernel(
    const float* __restrict__ protos, uint8_t* __restrict__ wsB,
    float* __restrict__ y2a, float* __restrict__ rya,
    float* __restrict__ out) {
  const int lane = threadIdx.x & 63;
  const int w    = threadIdx.x >> 6;
  const int kp2  = lane >> 2, q = lane & 3;   // writer coords (lanes 0..31)
  const int sl0  = 8 * kp2 + q;               // source lane of even half
  const int sl1  = sl0 + 4;                   // source lane of odd half
#pragma unroll
  for (int i = 0; i < 4; ++i) {
    int c = (blockIdx.x * 4 + w) * 4 + i;
    const float4* p = (const float4*)(protos + (size_t)c * 512 + lane * 8);
    float4 f0 = p[0], f1 = p[1];
    float s = f0.x*f0.x + f0.y*f0.y + f0.z*f0.z + f0.w*f0.w
            + f1.x*f1.x + f1.y*f1.y + f1.z*f1.z + f1.w*f1.w;
#pragma unroll
    for (int off = 32; off > 0; off >>= 1) s += __shfl_xor(s, off, 64);
    if (lane == 0) { y2a[c] = s; rya[c] = 1.f / (1.f - s); }
    unsigned ux = cvt4(f0.x, f0.y, f0.z, f0.w);   // this lane's k [8l, 8l+4)
    unsigned uy = cvt4(f1.x, f1.y, f1.z, f1.w);   // k [8l+4, 8l+8)
    uint4 ch;
    ch.x = __shfl((int)ux, sl0, 64);
    ch.y = __shfl((int)uy, sl0, 64);
    ch.z = __shfl((int)ux, sl1, 64);
    ch.w = __shfl((int)uy, sl1, 64);
    if (lane < 32) {
      int g = c >> 4, cl = c & 15;
      ((uint4*)wsB)[((size_t)g * 8 + kp2) * 64 + q * 16 + cl] = ch;
    }
  }
  if (blockIdx.x == 0 && threadIdx.x == 0) out[0] = 0.f;
}

// ---------------------------------------------------------------------------
// gemm_min: 512 blocks x 256 thr (4 waves), launch_bounds(256,2) ->
// 2 blocks/CU fully resident (8 waves/CU), VGPR cap 256 (actual ~160).
//   - A: 64 rows x 512 K fp8 staged ONCE into 32 KB LDS in A-fragment order;
//     x2 computed fp32-exact IN the staging pass (z read exactly once).
//     ONE barrier total before the main loop.
//   - B: register pipeline, depth 4 iters (8 b128 in flight) from the
//     L2/L3-resident pre-swizzled 1 MB fp8 image ~2500 cyc of MFMA work
//     ahead at full rate -> covers L3-class latency (~900 cyc) with margin.
//   - per iter (K=64): 4 ds_read_b128 (A, reused x2 across 2 col-frags),
//     2 global b128 (B, reused x4 across row-frags), 16 independent MFMAs.
//   - feeds at full MFMA rate: LDS 52 B/cyc (<85), B-L2 26 B/cyc (<56).
//   - epilogue per 32-col strip: tmin = min(tmin, max(x2+y2-2dot,0)*ry);
//     1/(1-x2) folded in once per row at the end (monotone, rx>0).
// ---------------------------------------------------------------------------
__global__ __launch_bounds__(256, 2) void gemm_min_kernel(
    const float* __restrict__ z, const uint8_t* __restrict__ wsB,
    const float* __restrict__ y2a, const float* __restrict__ rya,
    const float* __restrict__ marg, float* __restrict__ out) {
  __shared__ uint8_t As[32 * 1024];   // 32 chunks (kp2*4 + rf) x 64 lanes x 16B
  __shared__ float x2s[64];
  __shared__ float rxs[64];
  __shared__ float minbuf[64][4];

  const int tid  = threadIdx.x;
  const int lane = tid & 63;
  const int w    = tid >> 6;          // wave 0..3
  const int q    = lane >> 4;         // quad 0..3
  const int l15  = lane & 15;
  const size_t rowbase = (size_t)blockIdx.x * 64;

  // ---- A staging + fused x2: wave w owns rows w*16 + l15 ----
  // lane (q,l15) covers k slices [64j+8q,+8) and [64j+32+8q,+8) for j=0..7
  {
    const float* rp0 = z + (rowbase + w * 16 + l15) * 512;
    float s = 0.f;
#pragma unroll
    for (int j = 0; j < 8; ++j) {
      const float* rp = rp0 + j * 64 + q * 8;
      float4 a0 = ((const float4*)rp)[0];
      float4 a1 = ((const float4*)rp)[1];
      float4 b0 = ((const float4*)(rp + 32))[0];
      float4 b1 = ((const float4*)(rp + 32))[1];
      s += a0.x*a0.x + a0.y*a0.y + a0.z*a0.z + a0.w*a0.w
         + a1.x*a1.x + a1.y*a1.y + a1.z*a1.z + a1.w*a1.w
         + b0.x*b0.x + b0.y*b0.y + b0.z*b0.z + b0.w*b0.w
         + b1.x*b1.x + b1.y*b1.y + b1.z*b1.z + b1.w*b1.w;
      uint4 ch;
      ch.x = cvt4(a0.x, a0.y, a0.z, a0.w);
      ch.y = cvt4(a1.x, a1.y, a1.z, a1.w);
      ch.z = cvt4(b0.x, b0.y, b0.z, b0.w);
      ch.w = cvt4(b1.x, b1.y, b1.z, b1.w);
      ((uint4*)As)[(j * 4 + w) * 64 + lane] = ch;   // chunk = kp2*4 + rf(=w)
    }
    s += __shfl_xor(s, 16, 64);
    s += __shfl_xor(s, 32, 64);      // sum over the 4 q-lanes of this row
    if (lane < 16) { x2s[w * 16 + lane] = s; rxs[w * 16 + lane] = 1.f / (1.f - s); }
  }
  __syncthreads();  // the ONLY barrier before the final reduction

  // x2 resident per lane: rows rf*16 + q*4 + r
  float x2r[4][4];
#pragma unroll
  for (int rf = 0; rf < 4; ++rf) {
    float4 x4 = *(const float4*)&x2s[rf * 16 + q * 4];
    x2r[rf][0] = x4.x; x2r[rf][1] = x4.y; x2r[rf][2] = x4.z; x2r[rf][3] = x4.w;
  }

  const uint4* Ap = (const uint4*)As;
  const uint4* Bg = (const uint4*)wsB;

  // B pipeline: iter i = s*8 + kp2 consumes chunks c0 = w*256 + s*16 + kp2
  // and c1 = c0 + 8; slot = kp2 & 3 (inner loop unrolled -> compile-time).
  uint4 B0w[4], B1w[4];
#pragma unroll
  for (int i = 0; i < 4; ++i) {
    B0w[i] = Bg[(size_t)(w * 256 + i) * 64 + lane];
    B1w[i] = Bg[(size_t)(w * 256 + 8 + i) * 64 + lane];
  }

  float tmin[4][4];
#pragma unroll
  for (int rf = 0; rf < 4; ++rf)
#pragma unroll
    for (int r = 0; r < 4; ++r) tmin[rf][r] = 3.4e38f;

  const float* y2p = y2a + w * 512 + l15;
  const float* ryp = rya + w * 512 + l15;

#pragma clang loop unroll(disable)
  for (int s = 0; s < 16; ++s) {
    f32x4 acc[4][2];
#pragma unroll
    for (int rf = 0; rf < 4; ++rf) {
      f32x4 z4 = {0.f, 0.f, 0.f, 0.f};
      acc[rf][0] = z4; acc[rf][1] = z4;
    }
    float y2v0 = y2p[s * 32],      ryv0 = ryp[s * 32];
    float y2v1 = y2p[s * 32 + 16], ryv1 = ryp[s * 32 + 16];

#pragma unroll
    for (int kp2 = 0; kp2 < 8; ++kp2) {
      uint4 bu0 = B0w[kp2 & 3];
      uint4 bu1 = B1w[kp2 & 3];
      {  // prefetch iter i+4 into the just-freed slot (pad absorbs tail)
        int ip = s * 8 + kp2 + 4;
        int sp = ip >> 3, kq = ip & 7;
        size_t c0 = (size_t)(w * 256 + sp * 16 + kq) * 64 + lane;
        B0w[kp2 & 3] = Bg[c0];
        B1w[kp2 & 3] = Bg[c0 + 8 * 64];
      }
      A8 b0lo, b0hi, b1lo, b1hi;
      b0lo.u2 = make_uint2(bu0.x, bu0.y); b0hi.u2 = make_uint2(bu0.z, bu0.w);
      b1lo.u2 = make_uint2(bu1.x, bu1.y); b1hi.u2 = make_uint2(bu1.z, bu1.w);
#pragma unroll
      for (int rf = 0; rf < 4; ++rf) {
        uint4 av = Ap[(kp2 * 4 + rf) * 64 + lane];
        A8 alo, ahi;
        alo.u2 = make_uint2(av.x, av.y);
        ahi.u2 = make_uint2(av.z, av.w);
        acc[rf][0] = __builtin_amdgcn_mfma_f32_16x16x32_fp8_fp8(
            alo.l, b0lo.l, acc[rf][0], 0, 0, 0);
        acc[rf][1] = __builtin_amdgcn_mfma_f32_16x16x32_fp8_fp8(
            alo.l, b1lo.l, acc[rf][1], 0, 0, 0);
        acc[rf][0] = __builtin_amdgcn_mfma_f32_16x16x32_fp8_fp8(
            ahi.l, b0hi.l, acc[rf][0], 0, 0, 0);
        acc[rf][1] = __builtin_amdgcn_mfma_f32_16x16x32_fp8_fp8(
            ahi.l, b1hi.l, acc[rf][1], 0, 0, 0);
      }
    }

    // epilogue: cols c0 = w*512 + s*32 + l15, c1 = c0 + 16
#pragma unroll
    for (int rf = 0; rf < 4; ++rf) {
#pragma unroll
      for (int r = 0; r < 4; ++r) {
        float xv = x2r[rf][r];
        float u0 = fmaxf(fmaf(-2.f, acc[rf][0][r], xv + y2v0), 0.f) * ryv0;
        float u1 = fmaxf(fmaf(-2.f, acc[rf][1][r], xv + y2v1), 0.f) * ryv1;
        tmin[rf][r] = fminf(tmin[rf][r], fminf(u0, u1));
      }
    }
  }

  // ---- min across the 16 lanes (l15) sharing each row ----
#pragma unroll
  for (int rf = 0; rf < 4; ++rf) {
#pragma unroll
    for (int r = 0; r < 4; ++r) {
      float v = tmin[rf][r];
      v = fminf(v, __shfl_xor(v, 1, 64));
      v = fminf(v, __shfl_xor(v, 2, 64));
      v = fminf(v, __shfl_xor(v, 4, 64));
      v = fminf(v, __shfl_xor(v, 8, 64));
      if (l15 == 0) minbuf[rf * 16 + q * 4 + r][w] = v;
    }
  }
  __syncthreads();

  if (w == 0) {  // lane = row 0..63
    float m = fminf(fminf(minbuf[lane][0], minbuf[lane][1]),
                    fminf(minbuf[lane][2], minbuf[lane][3]));
    float t = m * rxs[lane];                 // fold 1/(1-x2) once per row
    float arg = fmaxf(fmaf(2.f, t, 1.f), 1.f + EPS_F);
    float contrib = fmaxf(marg[0] - acoshf(arg), 0.f);
#pragma unroll
    for (int off = 32; off > 0; off >>= 1) contrib += __shfl_xor(contrib, off, 64);
    if (lane == 0) atomicAdd(out, contrib * (1.0f / 32768.f));
  }
}

// ---------------------------------------------------------------------------
extern "C" void kernel_launch(void* const* d_in, const int* in_sizes, int n_in,
                              void* d_out, int out_size, void* d_ws, size_t ws_size,
                              hipStream_t stream) {
  const float* z      = (const float*)d_in[0];  // 32768 x 512 fp32
  const float* protos = (const float*)d_in[1];  // 2048 x 512 fp32
  const float* marg   = (const float*)d_in[2];  // scalar
  float* out = (float*)d_out;
  uint8_t* wsB = (uint8_t*)d_ws;                                 // 1 MB image
  // 192 KB pad absorbs the harmless B-pipeline tail over-reads (<= 64 KB).
  float* y2a = (float*)((char*)d_ws + (1 << 20) + 192 * 1024);   // 8 KB
  float* rya = y2a + 2048;                                       // 8 KB

  prep_kernel<<<128, 256, 0, stream>>>(protos, wsB, y2a, rya, out);
  gemm_min_kernel<<<512, 256, 0, stream>>>(z, wsB, y2a, rya, marg, out);
}